// Round 9
// baseline (11263.379 us; speedup 1.0000x reference)
//
#include <hip/hip_runtime.h>
#include <math.h>

#define Tn 64
#define Bn 32
#define INn 64
#define Nn 512
#define WDn 64
#define Rn 4
#define Hn 256
#define G4H 1024
#define OUTn 64
#define IFn 471
#define CLIPV 20.0f
#define EPSV 1e-6f

#define OFF_RKEY 0
#define OFF_RSTR 256
#define OFF_WKEY 260
#define OFF_WSTR 324
#define OFF_ERASE 325
#define OFF_WVEC 389
#define OFF_FREE 453
#define OFF_AG 457
#define OFF_WG 458
#define OFF_MODES 459

// ---------------- persistent device state (link lives in LDS now!) --------
__device__ float S_h[2][Bn][Hn];
__device__ float S_c[2][Bn][Hn];
__device__ float S_mem[Bn][Nn][WDn];
__device__ float S_rw[Bn][Rn][Nn];
__device__ float S_ww[2][Bn][Nn];
__device__ float S_prec[2][Bn][Nn];
__device__ float S_usage[2][Bn][Nn];
__device__ float S_reads[Bn][Rn][WDn];
__device__ float S_itf[Bn][IFn];
__device__ unsigned long long S_keys[Bn][Nn];
__device__ float S_alloc[Bn][Nn];
__device__ float S_wsim[Bn][Nn];
__device__ float S_rsim[Bn][Rn][Nn];
__device__ float S_fw[Bn][Rn][Nn];
__device__ float S_bwp[Bn][8][Rn*Nn];
__device__ float S_sumww[Bn];
// monotonic flags, 64B-padded
__device__ unsigned int g_tail[Bn][16];   // t+1 after tail(t)
__device__ unsigned int g_hb[Bn][16];     // 8(t+1) after all h(t) slices
__device__ unsigned int g_itf[Bn][16];    // 8(t+1)
__device__ unsigned int g_keys[Bn][16];   // 8(t+1)
__device__ unsigned int g_sim[Bn][16];    // 8(t+1)
__device__ unsigned int g_ww[Bn][16];     // t+1
__device__ unsigned int g_ld[Bn][16];     // 8(t+1) after mem+link per chunk

// ---------------- helpers ----------------
__device__ __forceinline__ float sigm(float x){ return 1.f/(1.f+expf(-x)); }
__device__ __forceinline__ float clipv(float x){ return fminf(fmaxf(x,-CLIPV),CLIPV); }
__device__ __forceinline__ float oneplusf(float x){
  float sp = (x > 0.f) ? (x + log1pf(expf(-x))) : log1pf(expf(x));
  return 1.f + sp;
}
__device__ __forceinline__ float wredsum(float v){
  #pragma unroll
  for (int o=32;o>0;o>>=1) v += __shfl_xor(v,o,64);
  return v;
}
__device__ __forceinline__ float bredsum(float v, volatile float* scr){
  v = wredsum(v);
  if ((threadIdx.x & 63) == 0) scr[threadIdx.x >> 6] = v;
  __syncthreads();
  float s = scr[0];
  #pragma unroll
  for (int i=1;i<8;i++) s += scr[i];
  __syncthreads();
  return s;
}
__device__ __forceinline__ float bredmax(float v, volatile float* scr){
  #pragma unroll
  for (int o=32;o>0;o>>=1) v = fmaxf(v,__shfl_xor(v,o,64));
  if ((threadIdx.x & 63) == 0) scr[threadIdx.x >> 6] = v;
  __syncthreads();
  float m = scr[0];
  #pragma unroll
  for (int i=1;i<8;i++) m = fmaxf(m, scr[i]);
  __syncthreads();
  return m;
}
__device__ __forceinline__ void sig_release(unsigned int* flag){
  __builtin_amdgcn_fence(__ATOMIC_RELEASE, "agent");
  __hip_atomic_fetch_add(flag, 1u, __ATOMIC_RELAXED, __HIP_MEMORY_SCOPE_AGENT);
}
__device__ __forceinline__ void wait_acq1(unsigned int* f, unsigned int tgt){
  if (threadIdx.x==0){
    while (__hip_atomic_load(f, __ATOMIC_RELAXED, __HIP_MEMORY_SCOPE_AGENT) < tgt)
      __builtin_amdgcn_s_sleep(2);
    __builtin_amdgcn_fence(__ATOMIC_ACQUIRE, "agent");
  }
  __syncthreads();
}

// ================= init =================
extern "C" __global__ void __launch_bounds__(256)
k_init(){
  size_t g = (size_t)blockIdx.x*256 + threadIdx.x;
  size_t stride = (size_t)gridDim.x*256;
  float* mm = &S_mem[0][0][0];
  for (size_t i=g; i<(size_t)Bn*Nn*WDn; i+=stride) mm[i]=0.f;
  float* rr = &S_rw[0][0][0];
  for (size_t i=g; i<(size_t)Bn*Rn*Nn; i+=stride) rr[i]=0.f;
  float* rd = &S_reads[0][0][0];
  for (size_t i=g; i<(size_t)Bn*Rn*WDn; i+=stride) rd[i]=0.f;
  for (size_t i=g; i<(size_t)2*Bn*Nn; i+=stride){
    S_ww[0][0][i]=0.f; S_prec[0][0][i]=0.f; S_usage[0][0][i]=0.f;
  }
  for (size_t i=g; i<(size_t)2*Bn*Hn; i+=stride){
    S_h[0][0][i]=0.f; S_c[0][0][i]=0.f;
  }
  if (blockIdx.x==0){
    for (int i=threadIdx.x; i<Bn*16; i+=256){
      ((unsigned int*)g_tail)[i]=0u; ((unsigned int*)g_hb)[i]=0u;
      ((unsigned int*)g_itf)[i]=0u;  ((unsigned int*)g_keys)[i]=0u;
      ((unsigned int*)g_sim)[i]=0u;  ((unsigned int*)g_ww)[i]=0u;
      ((unsigned int*)g_ld)[i]=0u;
    }
  }
}

// ---------------- LDS layouts ----------------
struct Fixed {
  float red[8];
  float knw;
  float knr[Rn];
  float betar[Rn];
  float modes[Rn][4];
  float wkey[WDn];
  float er[WDn], wv[WDn];
  float rk[Rn][WDn];
  float gval[128];
  float hc[Hn];
  float ipart[8][64];
};
struct ScrL { float ww[Nn]; float prec[Nn]; float rw[Rn][Nn]; float buf[4][Nn]; };
struct ScrT { float rs[Rn][Nn]; float part[8][Rn][WDn]; float vin[512]; };
union Scr {
  float ctrl[576];
  unsigned long long keys[Nn];
  ScrL l;
  ScrT t;
};

// ========== the persistent kernel: 256 blocks x 512, 1 block/CU ==========
// LDS: 128KB link chunk + ~26KB scratch -> 1 block/CU; 256 blocks on 256 CUs.
extern "C" __global__ void __launch_bounds__(512, 2)
k_all(const float* __restrict__ xin,
      const float* __restrict__ Wx, const float* __restrict__ Wh,
      const float* __restrict__ b_lstm,
      const float* __restrict__ W_if, const float* __restrict__ b_if,
      const float* __restrict__ W_out, const float* __restrict__ b_out,
      float* __restrict__ outp){
  __shared__ float link_lds[64*Nn];   // this block's 64 link rows, persistent
  __shared__ Fixed fx;
  __shared__ Scr scr;
  const int tid = threadIdx.x;
  const int lane = tid & 63, wvi = tid >> 6;
  const int bid = blockIdx.x;
  const int b = bid & 31, ch = bid >> 5;   // bid%8 == b%8 -> batch-XCD affinity
  const int i0 = ch*64;

  for (int k=tid;k<64*Nn;k+=512) link_lds[k]=0.f;
  __syncthreads();

  for (int t=0;t<Tn;++t){
    const int cur=t&1, prev=cur^1;
    // ============ G: gates slice + LSTM for h in [ch*32, ch*32+32) ========
    if (t>0) wait_acq1(&g_tail[b][0], (unsigned)t);
    for (int k=tid;k<576;k+=512){
      float v;
      if (k<INn)      v = xin[((size_t)t*Bn+b)*INn + k];
      else if (k<320) v = (t==0)?0.f : ((const float*)S_reads[b])[k-INn];
      else            v = (t==0)?0.f : S_h[prev][b][k-320];
      scr.ctrl[k]=v;
    }
    __syncthreads();
    {
      const int out = tid>>2, part = tid&3;
      const int gate = out>>5, hh = out&31;
      const int j = gate*256 + ch*32 + hh;
      float acc=0.f;
      const int kA0 = part*144, kA1 = kA0+144;
      const int kx1 = (kA1<320)?kA1:320;
      #pragma unroll 8
      for (int kk=kA0; kk<kx1; ++kk)
        acc += scr.ctrl[kk]*Wx[(size_t)kk*G4H + j];
      const int kh0 = (kA0>320)?kA0:320;
      #pragma unroll 8
      for (int kk=kh0; kk<kA1; ++kk)
        acc += scr.ctrl[kk]*Wh[(size_t)(kk-320)*G4H + j];
      acc += __shfl_xor(acc,1,64);
      acc += __shfl_xor(acc,2,64);
      if (part==0) fx.gval[out] = acc + b_lstm[j];
    }
    __syncthreads();
    if (tid<32){
      int h = ch*32+tid;
      float gi=fx.gval[tid], gf=fx.gval[32+tid], gg=fx.gval[64+tid], go=fx.gval[96+tid];
      float cold = S_c[prev][b][h];
      float cn = sigm(gf)*cold + sigm(gi)*tanhf(gg);
      float hn = sigm(go)*tanhf(cn);
      S_c[cur][b][h]=clipv(cn);
      S_h[cur][b][h]=clipv(hn);
    }
    __syncthreads();
    if (tid==0) sig_release(&g_hb[b][0]);

    // ============ I: itf slice [ch*59, ...) ============
    wait_acq1(&g_hb[b][0], 8u*(unsigned)(t+1));
    if (tid<Hn) fx.hc[tid] = S_h[cur][b][tid];
    __syncthreads();
    const int col0 = ch*59;
    const int ncol = (IFn - col0 < 59) ? (IFn - col0) : 59;
    {
      float acc=0.f;
      if (lane<ncol){
        const float* wp = W_if + (size_t)(wvi*32)*IFn + col0 + lane;
        #pragma unroll 8
        for (int kk=0;kk<32;++kk)
          acc += fx.hc[wvi*32+kk]*wp[(size_t)kk*IFn];
      }
      fx.ipart[wvi][lane]=acc;
    }
    __syncthreads();
    if (tid<ncol){
      float s = b_if[col0+tid];
      #pragma unroll
      for (int w=0;w<8;w++) s += fx.ipart[w][tid];
      S_itf[b][col0+tid]=s;
    }
    __syncthreads();
    if (tid==0) sig_release(&g_itf[b][0]);

    // ============ K: usage + sort-keys for own 64 n ============
    wait_acq1(&g_itf[b][0], 8u*(unsigned)(t+1));
    if (tid<64){
      float fg0=sigm(S_itf[b][OFF_FREE+0]), fg1=sigm(S_itf[b][OFF_FREE+1]);
      float fg2=sigm(S_itf[b][OFF_FREE+2]), fg3=sigm(S_itf[b][OFF_FREE+3]);
      int n = i0+tid;
      float uu = S_usage[prev][b][n], wwp = S_ww[prev][b][n];
      float u = uu + (1.f-uu)*wwp;
      float psi = (1.f - fg0*S_rw[b][0][n])*(1.f - fg1*S_rw[b][1][n])
                * (1.f - fg2*S_rw[b][2][n])*(1.f - fg3*S_rw[b][3][n]);
      float un = u*psi;
      S_usage[cur][b][n] = un;
      float v = EPSV + (1.f-EPSV)*un;
      S_keys[b][n] = ((unsigned long long)__float_as_uint(v) << 32) | (unsigned)n;
    }
    __syncthreads();
    if (tid==0) sig_release(&g_keys[b][0]);

    // ============ S: alloc + write-content sim for own 64 n ============
    wait_acq1(&g_keys[b][0], 8u*(unsigned)(t+1));
    scr.keys[tid] = S_keys[b][tid];
    if (tid<WDn) fx.wkey[tid] = S_itf[b][OFF_WKEY+tid];
    __syncthreads();
    if (wvi==0){
      float kv = fx.wkey[lane];
      float s2 = wredsum(kv*kv);
      if (lane==0) fx.knw = sqrtf(s2);
    }
    __syncthreads();
    {
      const int nn=tid>>3, q=tid&7, n=i0+nn;
      unsigned long long myk = scr.keys[n];
      float prod=1.f;
      #pragma unroll 8
      for (int jj=q*64; jj<q*64+64; ++jj){
        unsigned long long kj = scr.keys[jj];
        float uj = __uint_as_float((unsigned)(kj>>32));
        prod *= (kj < myk) ? uj : 1.f;
      }
      prod *= __shfl_xor(prod,1,64);
      prod *= __shfl_xor(prod,2,64);
      prod *= __shfl_xor(prod,4,64);
      float betaw = oneplusf(S_itf[b][OFF_WSTR]);
      const float4* mp = (const float4*)(&S_mem[b][n][q*8]);
      float4 ma = mp[0], mb2 = mp[1];
      float mv[8]; *(float4*)&mv[0]=ma; *(float4*)&mv[4]=mb2;
      float d=0.f, nrm=0.f;
      #pragma unroll
      for (int i2=0;i2<8;i2++){
        float m = mv[i2];
        d += m*fx.wkey[q*8+i2]; nrm += m*m;
      }
      #pragma unroll
      for (int o=1;o<8;o<<=1){ d += __shfl_xor(d,o,64); nrm += __shfl_xor(nrm,o,64); }
      if (q==0){
        float myu = __uint_as_float((unsigned)(myk>>32));
        S_alloc[b][n] = (1.f - myu)*prod;
        S_wsim[b][n]  = betaw * d / (fx.knw*sqrtf(nrm) + EPSV);
      }
    }
    __syncthreads();
    if (tid==0) sig_release(&g_sim[b][0]);

    // ============ W (ch==0): softmax + ww + sumww ============
    if (ch==0){
      wait_acq1(&g_sim[b][0], 8u*(unsigned)(t+1));
      float v  = S_wsim[b][tid];
      float al = S_alloc[b][tid];
      float mx = bredmax(v, fx.red);
      float e = expf(v - mx);
      float ssum = bredsum(e, fx.red);
      float wc = e/ssum;
      float ag = sigm(S_itf[b][OFF_AG]);
      float wg = sigm(S_itf[b][OFF_WG]);
      float wwv = wg*(ag*al + (1.f-ag)*wc);
      S_ww[cur][b][tid] = wwv;
      float wsum = bredsum(wwv, fx.red);
      if (tid==0) S_sumww[b] = wsum;
      __syncthreads();
      if (tid==0) sig_release(&g_ww[b][0]);
    }

    // ============ M: mem erase/write + rc-sims for own 64 rows ============
    wait_acq1(&g_ww[b][0], (unsigned)(t+1));
    if (tid<WDn){
      fx.er[tid] = sigm(S_itf[b][OFF_ERASE+tid]);
      fx.wv[tid] = S_itf[b][OFF_WVEC+tid];
    } else if (tid < WDn + Rn*WDn){
      int k2 = tid - WDn;
      fx.rk[k2>>6][k2&63] = S_itf[b][OFF_RKEY + k2];
    } else if (tid < WDn + Rn*WDn + Rn){
      fx.betar[tid-(WDn+Rn*WDn)] = oneplusf(S_itf[b][OFF_RSTR + tid-(WDn+Rn*WDn)]);
    }
    __syncthreads();
    if (wvi<4){
      float kv = fx.rk[wvi][lane];
      float s2 = wredsum(kv*kv);
      if (lane==0) fx.knr[wvi] = sqrtf(s2);
    }
    __syncthreads();
    {
      const int nn=tid>>3, q=tid&7, n=i0+nn;
      float wwn = S_ww[cur][b][n];
      float4* mp = (float4*)(&S_mem[b][n][q*8]);
      float4 ma=mp[0], mb2=mp[1];
      float mv[8]; *(float4*)&mv[0]=ma; *(float4*)&mv[4]=mb2;
      float a0=0.f,a1=0.f,a2=0.f,a3=0.f,nrm=0.f;
      #pragma unroll
      for (int i2=0;i2<8;i2++){
        int w = q*8+i2;
        float m = mv[i2];
        m = m*(1.f - wwn*fx.er[w]) + wwn*fx.wv[w];
        mv[i2]=m;
        a0 += m*fx.rk[0][w]; a1 += m*fx.rk[1][w];
        a2 += m*fx.rk[2][w]; a3 += m*fx.rk[3][w];
        nrm += m*m;
      }
      mp[0]=*(float4*)&mv[0]; mp[1]=*(float4*)&mv[4];
      #pragma unroll
      for (int o=1;o<8;o<<=1){
        a0+=__shfl_xor(a0,o,64); a1+=__shfl_xor(a1,o,64);
        a2+=__shfl_xor(a2,o,64); a3+=__shfl_xor(a3,o,64);
        nrm+=__shfl_xor(nrm,o,64);
      }
      if (q==0){
        float mn = sqrtf(nrm);
        S_rsim[b][0][n] = fx.betar[0]*a0/(fx.knr[0]*mn + EPSV);
        S_rsim[b][1][n] = fx.betar[1]*a1/(fx.knr[1]*mn + EPSV);
        S_rsim[b][2][n] = fx.betar[2]*a2/(fx.knr[2]*mn + EPSV);
        S_rsim[b][3][n] = fx.betar[3]*a3/(fx.knr[3]*mn + EPSV);
      }
    }
    __syncthreads();

    // ============ L: link update in LDS + fw/bw + prec ============
    scr.l.ww[tid]   = S_ww[cur][b][tid];
    scr.l.prec[tid] = S_prec[prev][b][tid];
    for (int k=tid;k<Rn*Nn;k+=512) ((float*)scr.l.rw)[k] = ((const float*)S_rw[b])[k];
    __syncthreads();
    {
      float sumww = S_sumww[b];
      float wj[2][4], pj[2][4], rj[4][2][4];
      #pragma unroll
      for (int jjc=0;jjc<2;jjc++){
        float4 w4 = ((const float4*)scr.l.ww)[jjc*64+lane];
        float4 p4 = ((const float4*)scr.l.prec)[jjc*64+lane];
        wj[jjc][0]=w4.x; wj[jjc][1]=w4.y; wj[jjc][2]=w4.z; wj[jjc][3]=w4.w;
        pj[jjc][0]=p4.x; pj[jjc][1]=p4.y; pj[jjc][2]=p4.z; pj[jjc][3]=p4.w;
        #pragma unroll
        for (int r=0;r<4;r++){
          float4 r4 = ((const float4*)scr.l.rw[r])[jjc*64+lane];
          rj[r][jjc][0]=r4.x; rj[r][jjc][1]=r4.y; rj[r][jjc][2]=r4.z; rj[r][jjc][3]=r4.w;
        }
      }
      float bwa[4][2][4];
      #pragma unroll
      for (int r=0;r<4;r++)
        #pragma unroll
        for (int jjc=0;jjc<2;jjc++)
          #pragma unroll
          for (int s=0;s<4;s++) bwa[r][jjc][s]=0.f;
      for (int rr=0;rr<8;rr++){
        const int row = wvi*8 + rr;
        const int i = i0 + row;
        float wi = scr.l.ww[i];
        float ci = 1.f - wi;
        float ri[4] = {scr.l.rw[0][i], scr.l.rw[1][i], scr.l.rw[2][i], scr.l.rw[3][i]};
        float f[4] = {0.f,0.f,0.f,0.f};
        float4* lrow4 = (float4*)(&link_lds[(size_t)row*Nn]);
        #pragma unroll
        for (int jjc=0;jjc<2;jjc++){
          float4 L4 = lrow4[jjc*64+lane];
          float Ls[4] = {L4.x, L4.y, L4.z, L4.w};
          #pragma unroll
          for (int s=0;s<4;s++){
            float Ln = (ci - wj[jjc][s])*Ls[s] + wi*pj[jjc][s];
            int j = jjc*256 + lane*4 + s;
            Ln = (j==i) ? 0.f : Ln;
            Ls[s] = Ln;
            #pragma unroll
            for (int r=0;r<4;r++){
              f[r] += Ln*rj[r][jjc][s];
              bwa[r][jjc][s] += Ln*ri[r];
            }
          }
          float4 Lo; Lo.x=Ls[0]; Lo.y=Ls[1]; Lo.z=Ls[2]; Lo.w=Ls[3];
          lrow4[jjc*64+lane] = Lo;
        }
        #pragma unroll
        for (int r=0;r<4;r++){
          float fr = wredsum(f[r]);
          if (lane==0) S_fw[b][r][i] = fr;
        }
      }
      // deterministic cross-wave bw reduce, one r at a time (8KB buffer)
      for (int r=0;r<4;r++){
        if (wvi>=4){
          int w = wvi-4;
          #pragma unroll
          for (int jjc=0;jjc<2;jjc++){
            float4 v4; v4.x=bwa[r][jjc][0]; v4.y=bwa[r][jjc][1]; v4.z=bwa[r][jjc][2]; v4.w=bwa[r][jjc][3];
            ((float4*)scr.l.buf[w])[jjc*64+lane] = v4;
          }
        }
        __syncthreads();
        if (wvi<4){
          #pragma unroll
          for (int jjc=0;jjc<2;jjc++){
            float4 v4 = ((float4*)scr.l.buf[wvi])[jjc*64+lane];
            v4.x+=bwa[r][jjc][0]; v4.y+=bwa[r][jjc][1]; v4.z+=bwa[r][jjc][2]; v4.w+=bwa[r][jjc][3];
            ((float4*)scr.l.buf[wvi])[jjc*64+lane] = v4;
          }
        }
        __syncthreads();
        {
          float s = scr.l.buf[0][tid]+scr.l.buf[1][tid]+scr.l.buf[2][tid]+scr.l.buf[3][tid];
          S_bwp[b][ch][r*Nn + tid] = s;
        }
        __syncthreads();
      }
      if (tid<64){
        int j = i0 + tid;
        S_prec[cur][b][j] = (1.f - sumww)*scr.l.prec[j] + scr.l.ww[j];
      }
    }
    __syncthreads();
    if (tid==0) sig_release(&g_ld[b][0]);

    // ============ T (ch==0): rc softmax + rw + reads + out ============
    if (ch==0){
      wait_acq1(&g_ld[b][0], 8u*(unsigned)(t+1));
      for (int k=tid;k<Rn*Nn;k+=512) ((float*)scr.t.rs)[k] = ((const float*)S_rsim[b])[k];
      if (tid<4){
        int r = tid;
        float m0 = S_itf[b][OFF_MODES + r*3 + 0];
        float m1 = S_itf[b][OFF_MODES + r*3 + 1];
        float m2 = S_itf[b][OFF_MODES + r*3 + 2];
        float mx = fmaxf(m0,fmaxf(m1,m2));
        float e0=expf(m0-mx), e1=expf(m1-mx), e2=expf(m2-mx);
        float si = e0+e1+e2;
        fx.modes[r][0]=e0/si; fx.modes[r][1]=e1/si; fx.modes[r][2]=e2/si;
      }
      __syncthreads();
      for (int r=0;r<Rn;r++){
        float v = scr.t.rs[r][tid];
        float mx = bredmax(v, fx.red);
        float e = expf(v - mx);
        float ssum = bredsum(e, fx.red);
        scr.t.rs[r][tid] = e/ssum;
      }
      __syncthreads();
      for (int k=tid;k<Rn*Nn;k+=512){
        int r = k>>9;
        float bwv = 0.f;
        #pragma unroll
        for (int c2=0;c2<8;c2++) bwv += S_bwp[b][c2][k];
        float v = fx.modes[r][2]*((float*)scr.t.rs)[k]
                + fx.modes[r][1]*((const float*)S_fw[b])[k]
                + fx.modes[r][0]*bwv;
        ((float*)scr.t.rs)[k] = v;
        ((float*)S_rw[b])[k] = v;
      }
      __syncthreads();
      {
        float a0=0.f,a1=0.f,a2=0.f,a3=0.f;
        #pragma unroll 4
        for (int nn=0;nn<64;nn++){
          int n = wvi*64+nn;
          float m = S_mem[b][n][lane];
          a0 += scr.t.rs[0][n]*m; a1 += scr.t.rs[1][n]*m;
          a2 += scr.t.rs[2][n]*m; a3 += scr.t.rs[3][n]*m;
        }
        scr.t.part[wvi][0][lane]=a0; scr.t.part[wvi][1][lane]=a1;
        scr.t.part[wvi][2][lane]=a2; scr.t.part[wvi][3][lane]=a3;
      }
      __syncthreads();
      if (tid < 256){
        int r = tid>>6, w = tid&63;
        float sv = 0.f;
        #pragma unroll
        for (int v=0;v<8;v++) sv += scr.t.part[v][r][w];
        S_reads[b][r][w] = sv;
        scr.t.vin[256+tid] = sv;
        scr.t.vin[tid] = S_h[cur][b][tid];
      }
      __syncthreads();
      {
        int qq = tid>>6, o = tid&63;
        float sacc = 0.f;
        for (int k2=qq*64;k2<qq*64+64;k2+=8){
          #pragma unroll
          for (int u=0;u<8;u++) sacc += scr.t.vin[k2+u]*W_out[(size_t)(k2+u)*OUTn + o];
        }
        scr.t.part[qq][0][o] = sacc;
      }
      __syncthreads();
      if (tid < 64){
        float sv = b_out[tid];
        #pragma unroll
        for (int qq=0;qq<8;qq++) sv += scr.t.part[qq][0][tid];
        outp[((size_t)t*Bn + b)*OUTn + tid] = clipv(sv);
      }
      __syncthreads();
      if (tid==0) sig_release(&g_tail[b][0]);
    }
  }
}

extern "C" void kernel_launch(void* const* d_in, const int* in_sizes, int n_in,
                              void* d_out, int out_size, void* d_ws, size_t ws_size,
                              hipStream_t stream){
  (void)in_sizes; (void)n_in; (void)d_ws; (void)ws_size; (void)out_size;
  const float* xin = (const float*)d_in[0];
  const float* Wx  = (const float*)d_in[1];
  const float* Wh  = (const float*)d_in[2];
  const float* bl  = (const float*)d_in[3];
  const float* Wif = (const float*)d_in[4];
  const float* bif = (const float*)d_in[5];
  const float* Wo  = (const float*)d_in[6];
  const float* bo  = (const float*)d_in[7];
  hipLaunchKernelGGL(k_init, dim3(256), dim3(256), 0, stream);
  hipLaunchKernelGGL(k_all, dim3(256), dim3(512), 0, stream,
                     xin, Wx, Wh, bl, Wif, bif, Wo, bo, (float*)d_out);
}

// Round 10
// 10807.602 us; speedup vs baseline: 1.0422x; 1.0422x over previous
//
#include <hip/hip_runtime.h>
#include <math.h>

#define Tn 64
#define Bn 32
#define INn 64
#define Nn 512
#define WDn 64
#define Rn 4
#define Hn 256
#define G4H 1024
#define OUTn 64
#define IFn 471
#define CLIPV 20.0f
#define EPSV 1e-6f

#define OFF_RKEY 0
#define OFF_RSTR 256
#define OFF_WKEY 260
#define OFF_WSTR 324
#define OFF_ERASE 325
#define OFF_WVEC 389
#define OFF_FREE 453
#define OFF_AG 457
#define OFF_WG 458
#define OFF_MODES 459

// ---------------- persistent device state (link lives in LDS) ----------
__device__ float S_h[2][Bn][Hn];
__device__ float S_c[2][Bn][Hn];
__device__ float S_mem[Bn][Nn][WDn];
__device__ float S_rw[Bn][Rn][Nn];
__device__ float S_ww[2][Bn][Nn];
__device__ float S_prec[2][Bn][Nn];
__device__ float S_usage[2][Bn][Nn];
__device__ float S_reads[Bn][Rn][WDn];
__device__ float S_itf[Bn][IFn];
__device__ unsigned long long S_keys[Bn][Nn];
__device__ float S_alloc[Bn][Nn];
__device__ float S_wsim[Bn][Nn];
__device__ float S_rsim[Bn][Rn][Nn];
__device__ float S_fw[Bn][Rn][Nn];
__device__ float S_bwp[Bn][8][Rn*Nn];
__device__ float S_sumww[Bn];
// monotonic flags, 64B-padded
__device__ unsigned int g_tail[Bn][16];
__device__ unsigned int g_hb[Bn][16];
__device__ unsigned int g_itf[Bn][16];
__device__ unsigned int g_keys[Bn][16];
__device__ unsigned int g_sim[Bn][16];
__device__ unsigned int g_ww[Bn][16];
__device__ unsigned int g_ld[Bn][16];

// ---------------- helpers ----------------
__device__ __forceinline__ float sigm(float x){ return 1.f/(1.f+expf(-x)); }
__device__ __forceinline__ float clipv(float x){ return fminf(fmaxf(x,-CLIPV),CLIPV); }
__device__ __forceinline__ float oneplusf(float x){
  float sp = (x > 0.f) ? (x + log1pf(expf(-x))) : log1pf(expf(x));
  return 1.f + sp;
}
__device__ __forceinline__ float wredsum(float v){
  #pragma unroll
  for (int o=32;o>0;o>>=1) v += __shfl_xor(v,o,64);
  return v;
}
__device__ __forceinline__ float bredsum(float v, volatile float* scr){
  v = wredsum(v);
  if ((threadIdx.x & 63) == 0) scr[threadIdx.x >> 6] = v;
  __syncthreads();
  float s = scr[0];
  #pragma unroll
  for (int i=1;i<8;i++) s += scr[i];
  __syncthreads();
  return s;
}
__device__ __forceinline__ float bredmax(float v, volatile float* scr){
  #pragma unroll
  for (int o=32;o>0;o>>=1) v = fmaxf(v,__shfl_xor(v,o,64));
  if ((threadIdx.x & 63) == 0) scr[threadIdx.x >> 6] = v;
  __syncthreads();
  float m = scr[0];
  #pragma unroll
  for (int i=1;i<8;i++) m = fmaxf(m, scr[i]);
  __syncthreads();
  return m;
}
__device__ __forceinline__ void sig_release(unsigned int* flag){
  __builtin_amdgcn_fence(__ATOMIC_RELEASE, "agent");
  __hip_atomic_fetch_add(flag, 1u, __ATOMIC_RELAXED, __HIP_MEMORY_SCOPE_AGENT);
}
__device__ __forceinline__ void wait_acq1(unsigned int* f, unsigned int tgt){
  if (threadIdx.x==0){
    while (__hip_atomic_load(f, __ATOMIC_RELAXED, __HIP_MEMORY_SCOPE_AGENT) < tgt)
      __builtin_amdgcn_s_sleep(2);
    __builtin_amdgcn_fence(__ATOMIC_ACQUIRE, "agent");
  }
  __syncthreads();
}

// ================= init =================
extern "C" __global__ void __launch_bounds__(256)
k_init(){
  size_t g = (size_t)blockIdx.x*256 + threadIdx.x;
  size_t stride = (size_t)gridDim.x*256;
  float* mm = &S_mem[0][0][0];
  for (size_t i=g; i<(size_t)Bn*Nn*WDn; i+=stride) mm[i]=0.f;
  float* rr = &S_rw[0][0][0];
  for (size_t i=g; i<(size_t)Bn*Rn*Nn; i+=stride) rr[i]=0.f;
  float* rd = &S_reads[0][0][0];
  for (size_t i=g; i<(size_t)Bn*Rn*WDn; i+=stride) rd[i]=0.f;
  for (size_t i=g; i<(size_t)2*Bn*Nn; i+=stride){
    S_ww[0][0][i]=0.f; S_prec[0][0][i]=0.f; S_usage[0][0][i]=0.f;
  }
  for (size_t i=g; i<(size_t)2*Bn*Hn; i+=stride){
    S_h[0][0][i]=0.f; S_c[0][0][i]=0.f;
  }
  if (blockIdx.x==0){
    for (int i=threadIdx.x; i<Bn*16; i+=256){
      ((unsigned int*)g_tail)[i]=0u; ((unsigned int*)g_hb)[i]=0u;
      ((unsigned int*)g_itf)[i]=0u;  ((unsigned int*)g_keys)[i]=0u;
      ((unsigned int*)g_sim)[i]=0u;  ((unsigned int*)g_ww)[i]=0u;
      ((unsigned int*)g_ld)[i]=0u;
    }
  }
}

// ---------------- LDS layouts ----------------
struct Fixed {
  float red[8];
  float knw;
  float knr[Rn];
  float betar[Rn];
  float modes[Rn][4];
  float wkey[WDn];
  float er[WDn], wv[WDn];
  float rk[Rn][WDn];
  float gval[128];
  float hc[Hn];
  float ipart[8][64];
};
struct ScrL { float ww[Nn]; float prec[Nn]; float rw[Rn][Nn]; float buf[4][Nn]; };
struct ScrT { float rs[Rn][Nn]; float part[8][Rn][WDn]; float vin[512]; };
union Scr {
  float ctrl[576];
  unsigned long long keys[Nn];
  ScrL l;
  ScrT t;
};

// ========== persistent kernel: 256 blocks x 512, 1 block/CU (LDS-bound) ====
extern "C" __global__ void __launch_bounds__(512, 2)
k_all(const float* __restrict__ xin,
      const float* __restrict__ Wx, const float* __restrict__ Wh,
      const float* __restrict__ b_lstm,
      const float* __restrict__ W_if, const float* __restrict__ b_if,
      const float* __restrict__ W_out, const float* __restrict__ b_out,
      float* __restrict__ outp){
  __shared__ float link_lds[64*Nn];   // this block's 64 link rows, persistent
  __shared__ Fixed fx;
  __shared__ Scr scr;
  const int tid = threadIdx.x;
  const int lane = tid & 63, wvi = tid >> 6;
  const int bid = blockIdx.x;
  const int b = bid & 31, ch = bid >> 5;   // bid%8 == b%8 -> batch-XCD affinity
  const int i0 = ch*64;

  for (int k=tid;k<64*Nn;k+=512) link_lds[k]=0.f;
  __syncthreads();

  for (int t=0;t<Tn;++t){
    const int cur=t&1, prev=cur^1;
    // ============ G: gates slice + LSTM for h in [ch*32, ch*32+32) ========
    if (t>0) wait_acq1(&g_tail[b][0], (unsigned)t);
    for (int k=tid;k<576;k+=512){
      float v;
      if (k<INn)      v = xin[((size_t)t*Bn+b)*INn + k];
      else if (k<320) v = (t==0)?0.f : ((const float*)S_reads[b])[k-INn];
      else            v = (t==0)?0.f : S_h[prev][b][k-320];
      scr.ctrl[k]=v;
    }
    __syncthreads();
    {
      const int out = tid>>2, part = tid&3;
      const int gate = out>>5, hh = out&31;
      const int j = gate*256 + ch*32 + hh;
      float acc=0.f;
      const int kA0 = part*144, kA1 = kA0+144;
      const int kx1 = (kA1<320)?kA1:320;
      #pragma unroll 8
      for (int kk=kA0; kk<kx1; ++kk)
        acc += scr.ctrl[kk]*Wx[(size_t)kk*G4H + j];
      const int kh0 = (kA0>320)?kA0:320;
      #pragma unroll 8
      for (int kk=kh0; kk<kA1; ++kk)
        acc += scr.ctrl[kk]*Wh[(size_t)(kk-320)*G4H + j];
      acc += __shfl_xor(acc,1,64);
      acc += __shfl_xor(acc,2,64);
      if (part==0) fx.gval[out] = acc + b_lstm[j];
    }
    __syncthreads();
    if (tid<32){
      int h = ch*32+tid;
      float gi=fx.gval[tid], gf=fx.gval[32+tid], gg=fx.gval[64+tid], go=fx.gval[96+tid];
      float cold = S_c[prev][b][h];
      float cn = sigm(gf)*cold + sigm(gi)*tanhf(gg);
      float hn = sigm(go)*tanhf(cn);
      S_c[cur][b][h]=clipv(cn);
      S_h[cur][b][h]=clipv(hn);
    }
    __syncthreads();
    if (tid==0) sig_release(&g_hb[b][0]);

    // ============ I: itf slice [ch*59, ...) ============
    wait_acq1(&g_hb[b][0], 8u*(unsigned)(t+1));
    if (tid<Hn) fx.hc[tid] = S_h[cur][b][tid];
    __syncthreads();
    const int col0 = ch*59;
    const int ncol = (IFn - col0 < 59) ? (IFn - col0) : 59;
    {
      float acc=0.f;
      if (lane<ncol){
        const float* wp = W_if + (size_t)(wvi*32)*IFn + col0 + lane;
        #pragma unroll 8
        for (int kk=0;kk<32;++kk)
          acc += fx.hc[wvi*32+kk]*wp[(size_t)kk*IFn];
      }
      fx.ipart[wvi][lane]=acc;
    }
    __syncthreads();
    if (tid<ncol){
      float s = b_if[col0+tid];
      #pragma unroll
      for (int w=0;w<8;w++) s += fx.ipart[w][tid];
      S_itf[b][col0+tid]=s;
    }
    __syncthreads();
    if (tid==0) sig_release(&g_itf[b][0]);

    // ============ K: usage + sort-keys for own 64 n ============
    wait_acq1(&g_itf[b][0], 8u*(unsigned)(t+1));
    if (tid<64){
      float fg0=sigm(S_itf[b][OFF_FREE+0]), fg1=sigm(S_itf[b][OFF_FREE+1]);
      float fg2=sigm(S_itf[b][OFF_FREE+2]), fg3=sigm(S_itf[b][OFF_FREE+3]);
      int n = i0+tid;
      float uu = S_usage[prev][b][n], wwp = S_ww[prev][b][n];
      float u = uu + (1.f-uu)*wwp;
      float psi = (1.f - fg0*S_rw[b][0][n])*(1.f - fg1*S_rw[b][1][n])
                * (1.f - fg2*S_rw[b][2][n])*(1.f - fg3*S_rw[b][3][n]);
      float un = u*psi;
      S_usage[cur][b][n] = un;
      float v = EPSV + (1.f-EPSV)*un;
      S_keys[b][n] = ((unsigned long long)__float_as_uint(v) << 32) | (unsigned)n;
    }
    __syncthreads();
    if (tid==0) sig_release(&g_keys[b][0]);

    // ============ S: alloc + write-content sim for own 64 n ============
    wait_acq1(&g_keys[b][0], 8u*(unsigned)(t+1));
    scr.keys[tid] = S_keys[b][tid];
    if (tid<WDn) fx.wkey[tid] = S_itf[b][OFF_WKEY+tid];
    __syncthreads();
    if (wvi==0){
      float kv = fx.wkey[lane];
      float s2 = wredsum(kv*kv);
      if (lane==0) fx.knw = sqrtf(s2);
    }
    __syncthreads();
    {
      const int nn=tid>>3, q=tid&7, n=i0+nn;
      unsigned long long myk = scr.keys[n];
      float prod=1.f;
      #pragma unroll 8
      for (int jj=q*64; jj<q*64+64; ++jj){
        unsigned long long kj = scr.keys[jj];
        float uj = __uint_as_float((unsigned)(kj>>32));
        prod *= (kj < myk) ? uj : 1.f;
      }
      prod *= __shfl_xor(prod,1,64);
      prod *= __shfl_xor(prod,2,64);
      prod *= __shfl_xor(prod,4,64);
      float betaw = oneplusf(S_itf[b][OFF_WSTR]);
      const float4* mp = (const float4*)(&S_mem[b][n][q*8]);
      float4 ma = mp[0], mb2 = mp[1];
      float mv[8]; *(float4*)&mv[0]=ma; *(float4*)&mv[4]=mb2;
      float d=0.f, nrm=0.f;
      #pragma unroll
      for (int i2=0;i2<8;i2++){
        float m = mv[i2];
        d += m*fx.wkey[q*8+i2]; nrm += m*m;
      }
      #pragma unroll
      for (int o=1;o<8;o<<=1){ d += __shfl_xor(d,o,64); nrm += __shfl_xor(nrm,o,64); }
      if (q==0){
        float myu = __uint_as_float((unsigned)(myk>>32));
        S_alloc[b][n] = (1.f - myu)*prod;
        S_wsim[b][n]  = betaw * d / (fx.knw*sqrtf(nrm) + EPSV);
      }
    }
    __syncthreads();
    if (tid==0) sig_release(&g_sim[b][0]);

    // ============ W (ch==0): softmax + ww + sumww ============
    if (ch==0){
      wait_acq1(&g_sim[b][0], 8u*(unsigned)(t+1));
      float v  = S_wsim[b][tid];
      float al = S_alloc[b][tid];
      float mx = bredmax(v, fx.red);
      float e = expf(v - mx);
      float ssum = bredsum(e, fx.red);
      float wc = e/ssum;
      float ag = sigm(S_itf[b][OFF_AG]);
      float wg = sigm(S_itf[b][OFF_WG]);
      float wwv = wg*(ag*al + (1.f-ag)*wc);
      S_ww[cur][b][tid] = wwv;
      float wsum = bredsum(wwv, fx.red);
      if (tid==0) S_sumww[b] = wsum;
      __syncthreads();
      if (tid==0) sig_release(&g_ww[b][0]);
    }

    // ============ M: mem erase/write + rc-sims for own 64 rows ============
    wait_acq1(&g_ww[b][0], (unsigned)(t+1));
    if (tid<WDn){
      fx.er[tid] = sigm(S_itf[b][OFF_ERASE+tid]);
      fx.wv[tid] = S_itf[b][OFF_WVEC+tid];
    } else if (tid < WDn + Rn*WDn){
      int k2 = tid - WDn;
      fx.rk[k2>>6][k2&63] = S_itf[b][OFF_RKEY + k2];
    } else if (tid < WDn + Rn*WDn + Rn){
      fx.betar[tid-(WDn+Rn*WDn)] = oneplusf(S_itf[b][OFF_RSTR + tid-(WDn+Rn*WDn)]);
    }
    __syncthreads();
    if (wvi<4){
      float kv = fx.rk[wvi][lane];
      float s2 = wredsum(kv*kv);
      if (lane==0) fx.knr[wvi] = sqrtf(s2);
    }
    __syncthreads();
    {
      const int nn=tid>>3, q=tid&7, n=i0+nn;
      float wwn = S_ww[cur][b][n];
      float4* mp = (float4*)(&S_mem[b][n][q*8]);
      float4 ma=mp[0], mb2=mp[1];
      float mv[8]; *(float4*)&mv[0]=ma; *(float4*)&mv[4]=mb2;
      float a0=0.f,a1=0.f,a2=0.f,a3=0.f,nrm=0.f;
      #pragma unroll
      for (int i2=0;i2<8;i2++){
        int w = q*8+i2;
        float m = mv[i2];
        m = m*(1.f - wwn*fx.er[w]) + wwn*fx.wv[w];
        mv[i2]=m;
        a0 += m*fx.rk[0][w]; a1 += m*fx.rk[1][w];
        a2 += m*fx.rk[2][w]; a3 += m*fx.rk[3][w];
        nrm += m*m;
      }
      mp[0]=*(float4*)&mv[0]; mp[1]=*(float4*)&mv[4];
      #pragma unroll
      for (int o=1;o<8;o<<=1){
        a0+=__shfl_xor(a0,o,64); a1+=__shfl_xor(a1,o,64);
        a2+=__shfl_xor(a2,o,64); a3+=__shfl_xor(a3,o,64);
        nrm+=__shfl_xor(nrm,o,64);
      }
      if (q==0){
        float mn = sqrtf(nrm);
        S_rsim[b][0][n] = fx.betar[0]*a0/(fx.knr[0]*mn + EPSV);
        S_rsim[b][1][n] = fx.betar[1]*a1/(fx.knr[1]*mn + EPSV);
        S_rsim[b][2][n] = fx.betar[2]*a2/(fx.knr[2]*mn + EPSV);
        S_rsim[b][3][n] = fx.betar[3]*a3/(fx.knr[3]*mn + EPSV);
      }
    }
    __syncthreads();

    // ============ L: link update in LDS (SCALAR layout: j=jj*64+lane) =====
    scr.l.ww[tid]   = S_ww[cur][b][tid];
    scr.l.prec[tid] = S_prec[prev][b][tid];
    for (int k=tid;k<Rn*Nn;k+=512) ((float*)scr.l.rw)[k] = ((const float*)S_rw[b])[k];
    __syncthreads();
    {
      float sumww = S_sumww[b];
      // register staging: j = jj*64 + lane (stride-4B LDS reads, conflict-free)
      float wj[8], pj[8], rj0[8], rj1[8], rj2[8], rj3[8];
      #pragma unroll
      for (int jj=0;jj<8;jj++){
        int j = jj*64+lane;
        wj[jj]=scr.l.ww[j]; pj[jj]=scr.l.prec[j];
        rj0[jj]=scr.l.rw[0][j]; rj1[jj]=scr.l.rw[1][j];
        rj2[jj]=scr.l.rw[2][j]; rj3[jj]=scr.l.rw[3][j];
      }
      float b0[8]={0,0,0,0,0,0,0,0}, b1[8]={0,0,0,0,0,0,0,0};
      float b2[8]={0,0,0,0,0,0,0,0}, b3[8]={0,0,0,0,0,0,0,0};
      for (int rr=0;rr<8;rr++){
        const int row = wvi*8 + rr;
        const int i = i0 + row;
        float wi = scr.l.ww[i];
        float ci = 1.f - wi;
        float ri0=scr.l.rw[0][i], ri1=scr.l.rw[1][i], ri2=scr.l.rw[2][i], ri3=scr.l.rw[3][i];
        float f0=0.f,f1=0.f,f2=0.f,f3=0.f;
        float* lrow = &link_lds[(size_t)row*Nn];
        #pragma unroll
        for (int jj=0;jj<8;jj++){
          int j = jj*64+lane;
          float L = lrow[j];                 // ds_read_b32, conflict-free
          float Ln = (ci - wj[jj])*L + wi*pj[jj];
          Ln = (j==i) ? 0.f : Ln;
          lrow[j] = Ln;                      // ds_write_b32, conflict-free
          f0 += Ln*rj0[jj]; f1 += Ln*rj1[jj]; f2 += Ln*rj2[jj]; f3 += Ln*rj3[jj];
          b0[jj] += Ln*ri0; b1[jj] += Ln*ri1; b2[jj] += Ln*ri2; b3[jj] += Ln*ri3;
        }
        f0=wredsum(f0); f1=wredsum(f1); f2=wredsum(f2); f3=wredsum(f3);
        if (lane==0){ S_fw[b][0][i]=f0; S_fw[b][1][i]=f1; S_fw[b][2][i]=f2; S_fw[b][3][i]=f3; }
      }
      // cross-wave bw reduce, scalar layout, one r at a time
      #pragma unroll
      for (int r=0;r<4;r++){
        const float* bsel = (r==0)?b0:(r==1)?b1:(r==2)?b2:b3;
        if (wvi>=4){
          int w = wvi-4;
          #pragma unroll
          for (int jj=0;jj<8;jj++) scr.l.buf[w][jj*64+lane] = bsel[jj];
        }
        __syncthreads();
        if (wvi<4){
          #pragma unroll
          for (int jj=0;jj<8;jj++) scr.l.buf[wvi][jj*64+lane] += bsel[jj];
        }
        __syncthreads();
        {
          float s = scr.l.buf[0][tid]+scr.l.buf[1][tid]+scr.l.buf[2][tid]+scr.l.buf[3][tid];
          S_bwp[b][ch][r*Nn + tid] = s;
        }
        __syncthreads();
      }
      if (tid<64){
        int j = i0 + tid;
        S_prec[cur][b][j] = (1.f - sumww)*scr.l.prec[j] + scr.l.ww[j];
      }
    }
    __syncthreads();
    if (tid==0) sig_release(&g_ld[b][0]);

    // ============ T (ch==0): rc softmax + rw + reads + out ============
    if (ch==0){
      wait_acq1(&g_ld[b][0], 8u*(unsigned)(t+1));
      for (int k=tid;k<Rn*Nn;k+=512) ((float*)scr.t.rs)[k] = ((const float*)S_rsim[b])[k];
      if (tid<4){
        int r = tid;
        float m0 = S_itf[b][OFF_MODES + r*3 + 0];
        float m1 = S_itf[b][OFF_MODES + r*3 + 1];
        float m2 = S_itf[b][OFF_MODES + r*3 + 2];
        float mx = fmaxf(m0,fmaxf(m1,m2));
        float e0=expf(m0-mx), e1=expf(m1-mx), e2=expf(m2-mx);
        float si = e0+e1+e2;
        fx.modes[r][0]=e0/si; fx.modes[r][1]=e1/si; fx.modes[r][2]=e2/si;
      }
      __syncthreads();
      for (int r=0;r<Rn;r++){
        float v = scr.t.rs[r][tid];
        float mx = bredmax(v, fx.red);
        float e = expf(v - mx);
        float ssum = bredsum(e, fx.red);
        scr.t.rs[r][tid] = e/ssum;
      }
      __syncthreads();
      for (int k=tid;k<Rn*Nn;k+=512){
        int r = k>>9;
        float bwv = 0.f;
        #pragma unroll
        for (int c2=0;c2<8;c2++) bwv += S_bwp[b][c2][k];
        float v = fx.modes[r][2]*((float*)scr.t.rs)[k]
                + fx.modes[r][1]*((const float*)S_fw[b])[k]
                + fx.modes[r][0]*bwv;
        ((float*)scr.t.rs)[k] = v;
        ((float*)S_rw[b])[k] = v;
      }
      __syncthreads();
      {
        float a0=0.f,a1=0.f,a2=0.f,a3=0.f;
        #pragma unroll 4
        for (int nn=0;nn<64;nn++){
          int n = wvi*64+nn;
          float m = S_mem[b][n][lane];
          a0 += scr.t.rs[0][n]*m; a1 += scr.t.rs[1][n]*m;
          a2 += scr.t.rs[2][n]*m; a3 += scr.t.rs[3][n]*m;
        }
        scr.t.part[wvi][0][lane]=a0; scr.t.part[wvi][1][lane]=a1;
        scr.t.part[wvi][2][lane]=a2; scr.t.part[wvi][3][lane]=a3;
      }
      __syncthreads();
      if (tid < 256){
        int r = tid>>6, w = tid&63;
        float sv = 0.f;
        #pragma unroll
        for (int v=0;v<8;v++) sv += scr.t.part[v][r][w];
        S_reads[b][r][w] = sv;
        scr.t.vin[256+tid] = sv;
        scr.t.vin[tid] = S_h[cur][b][tid];
      }
      __syncthreads();
      {
        int qq = tid>>6, o = tid&63;
        float sacc = 0.f;
        for (int k2=qq*64;k2<qq*64+64;k2+=8){
          #pragma unroll
          for (int u=0;u<8;u++) sacc += scr.t.vin[k2+u]*W_out[(size_t)(k2+u)*OUTn + o];
        }
        scr.t.part[qq][0][o] = sacc;
      }
      __syncthreads();
      if (tid < 64){
        float sv = b_out[tid];
        #pragma unroll
        for (int qq=0;qq<8;qq++) sv += scr.t.part[qq][0][tid];
        outp[((size_t)t*Bn + b)*OUTn + tid] = clipv(sv);
      }
      __syncthreads();
      if (tid==0) sig_release(&g_tail[b][0]);
    }
  }
}

extern "C" void kernel_launch(void* const* d_in, const int* in_sizes, int n_in,
                              void* d_out, int out_size, void* d_ws, size_t ws_size,
                              hipStream_t stream){
  (void)in_sizes; (void)n_in; (void)d_ws; (void)ws_size; (void)out_size;
  const float* xin = (const float*)d_in[0];
  const float* Wx  = (const float*)d_in[1];
  const float* Wh  = (const float*)d_in[2];
  const float* bl  = (const float*)d_in[3];
  const float* Wif = (const float*)d_in[4];
  const float* bif = (const float*)d_in[5];
  const float* Wo  = (const float*)d_in[6];
  const float* bo  = (const float*)d_in[7];
  hipLaunchKernelGGL(k_init, dim3(256), dim3(256), 0, stream);
  hipLaunchKernelGGL(k_all, dim3(256), dim3(512), 0, stream,
                     xin, Wx, Wh, bl, Wif, bif, Wo, bo, (float*)d_out);
}